// Round 1
// baseline (234.399 us; speedup 1.0000x reference)
//
#include <hip/hip_runtime.h>

#define BATCH 64
#define KSPEC 4
#define ROWS (BATCH * (KSPEC + 1))   // 320
#define VOCAB 128000

// ---------------------------------------------------------------------------
// Kernel 1: per-row argmax over VOCAB fp32 logits.
// One 1024-thread block per row. float4 coalesced loads.
// Tie-break: lowest index (matches jnp.argmax first-occurrence semantics).
// ---------------------------------------------------------------------------
__global__ __launch_bounds__(1024) void argmax_rows_kernel(
    const float* __restrict__ logits, int* __restrict__ row_argmax) {
    const int row = blockIdx.x;
    const int tid = threadIdx.x;
    const float4* rowp = (const float4*)(logits + (long long)row * VOCAB);
    const int nvec = VOCAB / 4;  // 32000

    float best = -__builtin_inff();
    int bidx = 0x7fffffff;

    for (int i = tid; i < nvec; i += 1024) {
        float4 v = rowp[i];
        int base = i * 4;
        if (v.x > best || (v.x == best && base     < bidx)) { best = v.x; bidx = base;     }
        if (v.y > best || (v.y == best && base + 1 < bidx)) { best = v.y; bidx = base + 1; }
        if (v.z > best || (v.z == best && base + 2 < bidx)) { best = v.z; bidx = base + 2; }
        if (v.w > best || (v.w == best && base + 3 < bidx)) { best = v.w; bidx = base + 3; }
    }

    // wave-level reduction (64 lanes)
    #pragma unroll
    for (int off = 32; off > 0; off >>= 1) {
        float ov = __shfl_down(best, off, 64);
        int   oi = __shfl_down(bidx, off, 64);
        if (ov > best || (ov == best && oi < bidx)) { best = ov; bidx = oi; }
    }

    __shared__ float svals[16];
    __shared__ int   sidx[16];
    const int wave = tid >> 6;
    const int lane = tid & 63;
    if (lane == 0) { svals[wave] = best; sidx[wave] = bidx; }
    __syncthreads();

    // final reduction: all 64 lanes of wave 0 participate (lanes >=16 get -inf)
    if (wave == 0) {
        best = (lane < 16) ? svals[lane] : -__builtin_inff();
        bidx = (lane < 16) ? sidx[lane]  : 0x7fffffff;
        #pragma unroll
        for (int off = 8; off > 0; off >>= 1) {
            float ov = __shfl_down(best, off, 64);
            int   oi = __shfl_down(bidx, off, 64);
            if (ov > best || (ov == best && oi < bidx)) { best = ov; bidx = oi; }
        }
        if (lane == 0) row_argmax[row] = bidx;
    }
}

// ---------------------------------------------------------------------------
// Kernel 2: rejection-accept logic. One thread per sequence.
// num_emitted = (# of leading spec-token matches) + 1; pad rest with -1.
// ---------------------------------------------------------------------------
__global__ void accept_kernel(const int* __restrict__ row_argmax,
                              const int* __restrict__ spec_ids,
                              int* __restrict__ out) {
    const int b = threadIdx.x;
    if (b >= BATCH) return;
    const int* ids = row_argmax + b * (KSPEC + 1);

    int num = 1;
    bool ok = true;
    #pragma unroll
    for (int i = 0; i < KSPEC; i++) {
        ok = ok && (spec_ids[b * KSPEC + i] == ids[i]);
        if (ok) num++;
    }
    #pragma unroll
    for (int i = 0; i <= KSPEC; i++) {
        out[b * (KSPEC + 1) + i] = (i < num) ? ids[i] : -1;
    }
}

extern "C" void kernel_launch(void* const* d_in, const int* in_sizes, int n_in,
                              void* d_out, int out_size, void* d_ws, size_t ws_size,
                              hipStream_t stream) {
    const float* logits  = (const float*)d_in[0];   // [320, 128000] fp32
    const int* spec_ids  = (const int*)d_in[1];     // [64, 4] int32
    int* out             = (int*)d_out;             // [64, 5] int32
    int* row_argmax      = (int*)d_ws;              // 320 ints scratch

    argmax_rows_kernel<<<ROWS, 1024, 0, stream>>>(logits, row_argmax);
    accept_kernel<<<1, 64, 0, stream>>>(row_argmax, spec_ids, out);
}

// Round 2
// 232.200 us; speedup vs baseline: 1.0095x; 1.0095x over previous
//
#include <hip/hip_runtime.h>

#define BATCH 64
#define KSPEC 4
#define ROWS (BATCH * (KSPEC + 1))   // 320
#define VOCAB 128000
#define NVEC  (VOCAB / 4)            // 32000 float4 per row
#define SEGS  8                      // segments per row
#define SEGV  (NVEC / SEGS)          // 4000 float4 per segment

// Monotone key: high 32 = order-preserving uint of float, low 32 = ~idx
// (so equal values tie-break to the SMALLEST index under u64 max).
__device__ __forceinline__ unsigned long long make_key(float f, int idx) {
    unsigned int u = __float_as_uint(f);
    u ^= ((unsigned int)((int)u >> 31)) | 0x80000000u;
    return ((unsigned long long)u << 32) | (unsigned int)(~idx);
}

__device__ __forceinline__ unsigned long long umax64(unsigned long long a,
                                                     unsigned long long b) {
    return a > b ? a : b;
}

// ---------------------------------------------------------------------------
// Phase 1: per-(row,segment) partial argmax. 2560 blocks x 256 threads
// = exactly 10 blocks/CU on 256 CUs, 512 KB read per row, coalesced float4.
// ---------------------------------------------------------------------------
__global__ __launch_bounds__(256) void argmax_partial_kernel(
    const float* __restrict__ logits, unsigned long long* __restrict__ partials) {
    const int blk = blockIdx.x;
    const int row = blk >> 3;        // / SEGS
    const int seg = blk & (SEGS - 1);
    const int tid = threadIdx.x;

    const float4* p = (const float4*)(logits + (long long)row * VOCAB) + seg * SEGV;
    const int base = seg * SEGV * 4;

    unsigned long long best = 0ull;  // below any finite key
    for (int i = tid; i < SEGV; i += 256) {
        float4 v = p[i];
        int idx = base + i * 4;
        best = umax64(best, make_key(v.x, idx));
        best = umax64(best, make_key(v.y, idx + 1));
        best = umax64(best, make_key(v.z, idx + 2));
        best = umax64(best, make_key(v.w, idx + 3));
    }

    // wave (64-lane) reduction
    #pragma unroll
    for (int off = 32; off > 0; off >>= 1)
        best = umax64(best, __shfl_down(best, off, 64));

    __shared__ unsigned long long sk[4];
    const int wave = tid >> 6;
    const int lane = tid & 63;
    if (lane == 0) sk[wave] = best;
    __syncthreads();

    if (tid == 0) {
        best = umax64(umax64(sk[0], sk[1]), umax64(sk[2], sk[3]));
        partials[blk] = best;
    }
}

// ---------------------------------------------------------------------------
// Phase 2: reduce 8 partials per row -> argmax idx, then accept logic.
// Single block of 384 threads.
// ---------------------------------------------------------------------------
__global__ void finalize_kernel(const unsigned long long* __restrict__ partials,
                                const int* __restrict__ spec_ids,
                                int* __restrict__ out) {
    __shared__ int sidx[ROWS];
    const int t = threadIdx.x;

    if (t < ROWS) {
        unsigned long long best = partials[t * SEGS];
        #pragma unroll
        for (int j = 1; j < SEGS; j++)
            best = umax64(best, partials[t * SEGS + j]);
        sidx[t] = (int)(~(unsigned int)best);   // recover idx from low 32 bits
    }
    __syncthreads();

    if (t < BATCH) {
        const int* ids = sidx + t * (KSPEC + 1);
        int num = 1;
        bool ok = true;
        #pragma unroll
        for (int i = 0; i < KSPEC; i++) {
            ok = ok && (spec_ids[t * KSPEC + i] == ids[i]);
            if (ok) num++;
        }
        #pragma unroll
        for (int i = 0; i <= KSPEC; i++)
            out[t * (KSPEC + 1) + i] = (i < num) ? ids[i] : -1;
    }
}

extern "C" void kernel_launch(void* const* d_in, const int* in_sizes, int n_in,
                              void* d_out, int out_size, void* d_ws, size_t ws_size,
                              hipStream_t stream) {
    const float* logits = (const float*)d_in[0];   // [320, 128000] fp32
    const int* spec_ids = (const int*)d_in[1];     // [64, 4] int32
    int* out            = (int*)d_out;             // [64, 5] int32
    unsigned long long* partials = (unsigned long long*)d_ws;  // 2560 u64

    argmax_partial_kernel<<<ROWS * SEGS, 256, 0, stream>>>(logits, partials);
    finalize_kernel<<<1, 384, 0, stream>>>(partials, spec_ids, out);
}

// Round 3
// 198.346 us; speedup vs baseline: 1.1818x; 1.1707x over previous
//
#include <hip/hip_runtime.h>

#define BATCH 64
#define KSPEC 4
#define GROUP (KSPEC + 1)            // 5 rows per sequence
#define ROWS (BATCH * GROUP)         // 320
#define VOCAB 128000
#define NVEC  (VOCAB / 4)            // 32000 float4 per row
#define SEGS  16                     // segments per row (phase A)
#define SEGV  (NVEC / SEGS)          // 2000 float4 per segment

// Monotone key: high 32 = order-preserving uint of float, low 32 = ~idx
// (equal values tie-break to the SMALLEST index under u64 max).
__device__ __forceinline__ unsigned long long make_key(float f, int idx) {
    unsigned int u = __float_as_uint(f);
    u ^= ((unsigned int)((int)u >> 31)) | 0x80000000u;
    return ((unsigned long long)u << 32) | (unsigned int)(~idx);
}

__device__ __forceinline__ unsigned long long umax64(unsigned long long a,
                                                     unsigned long long b) {
    return a > b ? a : b;
}

// ---------------------------------------------------------------------------
// Phase A: partial argmax of the 64 FIRST-spec rows only (row = b*GROUP).
// 64 rows x 16 segs = 1024 blocks x 256 threads (4 blocks/CU, 16 waves/CU).
// ---------------------------------------------------------------------------
__global__ __launch_bounds__(256) void argmax_first_rows_kernel(
    const float* __restrict__ logits, unsigned long long* __restrict__ partials) {
    const int blk = blockIdx.x;
    const int b   = blk >> 4;            // sequence
    const int seg = blk & (SEGS - 1);
    const int tid = threadIdx.x;

    const long long row = (long long)b * GROUP;   // first spec row of seq b
    const float4* p = (const float4*)(logits + row * VOCAB) + seg * SEGV;
    const int base = seg * SEGV * 4;

    unsigned long long best = 0ull;
    for (int i = tid; i < SEGV; i += 256) {
        float4 v = p[i];
        int idx = base + i * 4;
        best = umax64(best, make_key(v.x, idx));
        best = umax64(best, make_key(v.y, idx + 1));
        best = umax64(best, make_key(v.z, idx + 2));
        best = umax64(best, make_key(v.w, idx + 3));
    }

    #pragma unroll
    for (int off = 32; off > 0; off >>= 1)
        best = umax64(best, __shfl_down(best, off, 64));

    __shared__ unsigned long long sk[4];
    const int wave = tid >> 6;
    if ((tid & 63) == 0) sk[wave] = best;
    __syncthreads();

    if (tid == 0) {
        best = umax64(umax64(sk[0], sk[1]), umax64(sk[2], sk[3]));
        partials[blk] = best;
    }
}

// ---------------------------------------------------------------------------
// Phase B: one 1024-thread block per sequence. Fast path: reject at token 0
// (almost always for random data) -> write [id0, -1, -1, -1, -1].
// Slow path (any match): compute further row argmaxes in-block, on demand.
// ---------------------------------------------------------------------------
__global__ __launch_bounds__(1024) void finalize_kernel(
    const float* __restrict__ logits,
    const unsigned long long* __restrict__ partials,
    const int* __restrict__ spec_ids,
    int* __restrict__ out) {
    const int b   = blockIdx.x;
    const int tid = threadIdx.x;

    __shared__ int ids[GROUP];
    __shared__ int s_num;
    __shared__ unsigned long long sk[16];

    // reduce this sequence's 16 partials -> argmax of first spec row
    if (tid == 0) {
        unsigned long long best = partials[b * SEGS];
        #pragma unroll
        for (int j = 1; j < SEGS; j++)
            best = umax64(best, partials[b * SEGS + j]);
        ids[0] = (int)(~(unsigned int)best);
        s_num = 1;
    }
    __syncthreads();

    // slow path: walk forward while tokens match
    bool ok = (spec_ids[b * KSPEC + 0] == ids[0]);
    for (int i = 1; ok && i <= KSPEC; i++) {
        // block-wide argmax of row b*GROUP + i
        const float4* p = (const float4*)(logits + ((long long)b * GROUP + i) * VOCAB);
        unsigned long long best = 0ull;
        for (int j = tid; j < NVEC; j += 1024) {
            float4 v = p[j];
            int idx = j * 4;
            best = umax64(best, make_key(v.x, idx));
            best = umax64(best, make_key(v.y, idx + 1));
            best = umax64(best, make_key(v.z, idx + 2));
            best = umax64(best, make_key(v.w, idx + 3));
        }
        #pragma unroll
        for (int off = 32; off > 0; off >>= 1)
            best = umax64(best, __shfl_down(best, off, 64));
        if ((tid & 63) == 0) sk[tid >> 6] = best;
        __syncthreads();
        if (tid == 0) {
            unsigned long long r = sk[0];
            #pragma unroll
            for (int w = 1; w < 16; w++) r = umax64(r, sk[w]);
            ids[i] = (int)(~(unsigned int)r);
            s_num = i + 1;
        }
        __syncthreads();
        ok = (i < KSPEC) ? (spec_ids[b * KSPEC + i] == ids[i]) : false;
        __syncthreads();   // protect sk reuse next iteration
    }

    if (tid < GROUP) {
        int num = s_num;
        out[b * GROUP + tid] = (tid < num) ? ids[tid] : -1;
    }
}

extern "C" void kernel_launch(void* const* d_in, const int* in_sizes, int n_in,
                              void* d_out, int out_size, void* d_ws, size_t ws_size,
                              hipStream_t stream) {
    const float* logits = (const float*)d_in[0];   // [320, 128000] fp32
    const int* spec_ids = (const int*)d_in[1];     // [64, 4] int32
    int* out            = (int*)d_out;             // [64, 5] int32
    unsigned long long* partials = (unsigned long long*)d_ws;  // 1024 u64

    argmax_first_rows_kernel<<<BATCH * SEGS, 256, 0, stream>>>(logits, partials);
    finalize_kernel<<<BATCH, 1024, 0, stream>>>(logits, partials, spec_ids, out);
}